// Round 4
// baseline (80.342 us; speedup 1.0000x reference)
//
#include <hip/hip_runtime.h>
#include <math.h>

#define NB 64      // batch
#define NN 256     // elements per batch
#define NPAIRS 32640.0f   // N*(N-1)/2
#define EPSF 1e-8f
#define MAGIC 0x5CA1AB1Eu

// ws layout (floats):
//   per-batch  [11][64]   at 0    : 0 noise,1 posmse,2 iou,3 layermse,4 conf,
//                                   5 golden,6 areaSum,7 area2Sum,8 cxSum,9 cySum,10 vc
//   per-block  [3][512]   at 704  : 0 rank, 1 overlap, 2 align
//   flags      [512] u32  at 2240
#define PB(q) ((q) * 64)
#define PW(q) (704 + (q) * 512)
#define FLAGS_OFF 2240

// Block-wide sum for 256 threads (4 waves of 64). Result valid on ALL threads.
__device__ __forceinline__ float block_sum(float v, float* sred) {
    const int tid = threadIdx.x;
    #pragma unroll
    for (int off = 32; off > 0; off >>= 1) v += __shfl_down(v, off, 64);
    __syncthreads();                 // previous readers of sred are done
    if ((tid & 63) == 0) sred[tid >> 6] = v;
    __syncthreads();
    return sred[0] + sred[1] + sred[2] + sred[3];
}

__global__ __launch_bounds__(256) void loss_fused(
    const float* __restrict__ pn, const float* __restrict__ tn,
    const float* __restrict__ pl, const float* __restrict__ tl,
    const float* __restrict__ mask, float* __restrict__ ws,
    float* __restrict__ out)
{
    // packed pair fields: sA = {x1, y1, x2, y2}, sB = {cx, cy, area, p_layer},
    // sC = {t_layer, m}
    __shared__ float4 sA[NN], sB[NN];
    __shared__ float2 sC[NN];
    __shared__ float sred[4];
    __shared__ float bcx[NB], bcy[NB], bvc[NB];   // finalizer only

    const int b     = blockIdx.x >> 3;   // batch
    const int chunk = blockIdx.x & 7;    // pair-distance chunk / scalar-duty chunk
    const int i     = threadIdx.x;       // element within batch
    const int e     = b * NN + i;
    const float m   = mask[e];

    // vectorized row loads (rows are 24B-aligned -> float2 ok)
    const float2* pl2 = (const float2*)pl;
    const float2* tl2 = (const float2*)tl;
    const int r2 = e * 3;
    const float2 pla = pl2[r2 + 0], plb = pl2[r2 + 1], plc = pl2[r2 + 2];
    const float2 tlc = tl2[r2 + 2];

    const float p0 = pla.x * m, p1 = pla.y * m,
                p2 = plb.x * m, p3 = plb.y * m,
                p4 = plc.x * m, p5 = plc.y * m;
    const float t4 = tlc.x * m, t5 = tlc.y * m;

    const float x2v = p0 + p2, y2v = p1 + p3;
    const float areav = p2 * p3;
    const float cxe = p0 + 0.5f * p2, cye = p1 + 0.5f * p3;

    sA[i] = make_float4(p0, p1, x2v, y2v);
    sB[i] = make_float4(cxe, cye, areav, p4);
    sC[i] = make_float2(t4, m);
    __syncthreads();

    // ---------------- pairwise terms (this chunk's 16-dd range) -------------
    float rank = 0.f, ovl = 0.f, aln = 0.f;
    const int dd0 = chunk * 16 + 1;
    #pragma unroll 8
    for (int dd = dd0; dd < dd0 + 16; ++dd) {
        int j = (i + dd) & 255;
        if (dd == 128 && i >= 128) continue;   // dd=128 pairs counted once (i<j)
        float4 aj = sA[j];
        float4 bj = sB[j];
        float2 cj = sC[j];
        float pv = m * cj.y;
        // overlap
        float ow = fmaxf(fminf(x2v, aj.z) - fmaxf(p0, aj.x), 0.f);
        float oh = fmaxf(fminf(y2v, aj.w) - fmaxf(p1, aj.y), 0.f);
        ovl += ow * oh / (fminf(areav, bj.z) + EPSF) * pv;
        // alignment (6 edge types, dist<5 -> dist/5; /5 folded into 0.2f)
        float pen = 0.f, d;
        d = fabsf(p0  - aj.x); pen += (d < 5.f) ? d : 0.f;
        d = fabsf(x2v - aj.z); pen += (d < 5.f) ? d : 0.f;
        d = fabsf(p1  - aj.y); pen += (d < 5.f) ? d : 0.f;
        d = fabsf(y2v - aj.w); pen += (d < 5.f) ? d : 0.f;
        d = fabsf(cxe - bj.x); pen += (d < 5.f) ? d : 0.f;
        d = fabsf(cye - bj.y); pen += (d < 5.f) ? d : 0.f;
        aln += pen * 0.2f * pv;
        // ranking BCE on ordered (lo,hi)=(min(i,j),max(i,j)): diff = p[hi]-p[lo]
        bool ilt = (i < j);
        float dlo = ilt ? (bj.w - p4) : (p4 - bj.w);
        float ylo = (ilt ? (t4 < cj.x) : (cj.x < t4)) ? 1.f : 0.f;
        float sp  = __logf(1.f + __expf(-fabsf(dlo)));   // stable softplus core
        float sp_pos = sp + fmaxf(dlo, 0.f);             // softplus(+diff)
        float sp_neg = sp + fmaxf(-dlo, 0.f);            // softplus(-diff)
        rank += ylo * fminf(sp_neg, 100.f) + (1.f - ylo) * fminf(sp_pos, 100.f);
    }

    // pairwise per-block sums (all chunks)
    float s;
    s = block_sum(rank, sred); if (i == 0) ws[PW(0) + blockIdx.x] = s;
    s = block_sum(ovl,  sred); if (i == 0) ws[PW(1) + blockIdx.x] = s;
    s = block_sum(aln,  sred); if (i == 0) ws[PW(2) + blockIdx.x] = s;

    // ---------------- elementwise terms: distributed across 8 chunks --------
    switch (chunk) {
    case 0: {
        // noise SmoothL1 (only this chunk touches pn/tn)
        const float2* pn2 = (const float2*)pn;
        const float2* tn2 = (const float2*)tn;
        float noise = 0.f;
        #pragma unroll
        for (int k = 0; k < 3; ++k) {
            float2 a = pn2[r2 + k], bb = tn2[r2 + k];
            float d0 = fabsf(a.x * m - bb.x * m);
            float d1 = fabsf(a.y * m - bb.y * m);
            noise += (d0 < 1.f) ? 0.5f * d0 * d0 : d0 - 0.5f;
            noise += (d1 < 1.f) ? 0.5f * d1 * d1 : d1 - 0.5f;
        }
        s = block_sum(noise, sred); if (i == 0) ws[PB(0) + b] = s;
        break; }
    case 1: {
        const float2 tla = tl2[r2 + 0], tlb = tl2[r2 + 1];
        const float t0 = tla.x * m, t1 = tla.y * m,
                    t2 = tlb.x * m, t3 = tlb.y * m;
        float posmse = (p0 - t0) * (p0 - t0) + (p1 - t1) * (p1 - t1)
                     + (p2 - t2) * (p2 - t2) + (p3 - t3) * (p3 - t3);
        const float tx2 = t0 + t2, ty2 = t1 + t3;
        float iw = fmaxf(fminf(x2v, tx2) - fmaxf(p0, t0), 0.f);
        float ih = fmaxf(fminf(y2v, ty2) - fmaxf(p1, t1), 0.f);
        float inter = iw * ih;
        float iouL = 1.f - inter / (areav + t2 * t3 - inter + EPSF);
        s = block_sum(posmse, sred); if (i == 0) ws[PB(1) + b] = s;
        s = block_sum(iouL,   sred); if (i == 0) ws[PB(2) + b] = s;
        break; }
    case 2: {
        float lmse = (p4 - t4) * (p4 - t4);
        float cmse = (p5 - t5) * (p5 - t5);
        s = block_sum(lmse, sred); if (i == 0) ws[PB(3) + b] = s;
        s = block_sum(cmse, sred); if (i == 0) ws[PB(4) + b] = s;
        break; }
    case 3: {
        float golden = fabsf(p2 / (p3 + EPSF) - 1.618f);
        s = block_sum(golden, sred); if (i == 0) ws[PB(5) + b] = s;
        break; }
    case 4: {
        float areaA = areav * m;
        s = block_sum(areaA, sred); if (i == 0) ws[PB(6) + b] = s;
        break; }
    case 5: {
        float areaA = areav * m;
        s = block_sum(areaA * areaA, sred); if (i == 0) ws[PB(7) + b] = s;
        break; }
    case 6: {
        float cxA = cxe * m, cyA = cye * m;
        s = block_sum(cxA, sred); if (i == 0) ws[PB(8) + b] = s;
        s = block_sum(cyA, sred); if (i == 0) ws[PB(9) + b] = s;
        break; }
    default: {
        s = block_sum(m, sred); if (i == 0) ws[PB(10) + b] = s;
        break; }
    }

    // ---------------- publish: release flag (poison 0xAAAAAAAA != MAGIC) ----
    unsigned int* flags = (unsigned int*)(ws + FLAGS_OFF);
    if (i == 0) {
        __hip_atomic_store(&flags[blockIdx.x], MAGIC,
                           __ATOMIC_RELEASE, __HIP_MEMORY_SCOPE_AGENT);
    }
    if (blockIdx.x != 0) return;

    // ---------------- block 0: wait for all 512 blocks, then finalize -------
    {
        bool f1 = false, f2 = false;
        while (!(f1 && f2)) {
            if (!f1) f1 = (__hip_atomic_load(&flags[i],
                            __ATOMIC_ACQUIRE, __HIP_MEMORY_SCOPE_AGENT) == MAGIC);
            if (!f2) f2 = (__hip_atomic_load(&flags[256 + i],
                            __ATOMIC_ACQUIRE, __HIP_MEMORY_SCOPE_AGENT) == MAGIC);
            if (!(f1 && f2)) __builtin_amdgcn_s_sleep(8);
        }
    }
    __syncthreads();

    const int t = i;
    float v_noise = 0.f, v_pos = 0.f, v_iou = 0.f, v_lm = 0.f, v_cf = 0.f,
          v_go = 0.f, v_ar = 0.f, v_std = 0.f;
    if (t < NB) {
        v_noise = ws[PB(0) + t];
        v_pos   = ws[PB(1) + t];
        v_iou   = ws[PB(2) + t];
        v_lm    = ws[PB(3) + t];
        v_cf    = ws[PB(4) + t];
        v_go    = ws[PB(5) + t];
        v_ar    = ws[PB(6) + t];
        float a2 = ws[PB(7) + t];
        // per-row std, ddof=1
        float var = (a2 - v_ar * v_ar * (1.f / 256.f)) * (1.f / 255.f);
        v_std = sqrtf(fmaxf(var, 0.f));
        bcx[t] = ws[PB(8) + t];
        bcy[t] = ws[PB(9) + t];
        bvc[t] = ws[PB(10) + t];
    }
    // 512 pair-partials per term, 2 per thread
    float v_rank = ws[PW(0) + t] + ws[PW(0) + 256 + t];
    float v_ovl  = ws[PW(1) + t] + ws[PW(1) + 256 + t];
    float v_aln  = ws[PW(2) + t] + ws[PW(2) + 256 + t];
    __syncthreads();

    // faithful [B,B] balance broadcast: ocx[i,j] = sumcx[j]/(vc[i]+EPS)
    float v_bal = 0.f;
    if (t < NB) {
        float inv = 1.f / (bvc[t] + EPSF);
        for (int j = 0; j < NB; ++j) {
            v_bal += fabsf(bcx[j] * inv - 512.f) * (1.f / 512.f)
                   + fabsf(bcy[j] * inv - 512.f) * (1.f / 512.f);
        }
    }

    float S_noise = block_sum(v_noise, sred);
    float S_pos   = block_sum(v_pos,   sred);
    float S_iou   = block_sum(v_iou,   sred);
    float S_lm    = block_sum(v_lm,    sred);
    float S_cf    = block_sum(v_cf,    sred);
    float S_go    = block_sum(v_go,    sred);
    float S_ar    = block_sum(v_ar,    sred);
    float S_std   = block_sum(v_std,   sred);
    float S_bal   = block_sum(v_bal,   sred);
    float S_rank  = block_sum(v_rank,  sred);
    float S_ovl   = block_sum(v_ovl,   sred);
    float S_aln   = block_sum(v_aln,   sred);

    if (t == 0) {
        const float BN = 64.f * 256.f;
        float noise_loss = S_noise / (BN * 6.f);
        float position   = S_pos / (BN * 4.f) + 0.5f * (S_iou / BN);
        float layer      = S_lm / BN + 0.3f * (S_rank / (64.f * NPAIRS));
        float conf       = S_cf / BN;
        float golden     = S_go / BN;
        float size_harm  = (S_std / 64.f) / (S_ar / BN + EPSF);
        float balance    = S_bal / 4096.f;
        float aes        = 0.1f * golden + 0.2f * size_harm + 0.15f * balance;
        float ovl        = S_ovl / (64.f * NPAIRS);
        float aln        = S_aln / (64.f * 6.f * NPAIRS);
        out[0] = noise_loss + position + 0.5f * layer + 0.3f * conf
               + 0.2f * aes + 0.8f * ovl + 0.4f * aln;
    }
}

extern "C" void kernel_launch(void* const* d_in, const int* in_sizes, int n_in,
                              void* d_out, int out_size, void* d_ws, size_t ws_size,
                              hipStream_t stream) {
    const float* pn   = (const float*)d_in[0];
    const float* tn   = (const float*)d_in[1];
    const float* pl   = (const float*)d_in[2];
    const float* tl   = (const float*)d_in[3];
    const float* mask = (const float*)d_in[4];
    float* ws  = (float*)d_ws;
    float* out = (float*)d_out;
    hipLaunchKernelGGL(loss_fused, dim3(512), dim3(256), 0, stream,
                       pn, tn, pl, tl, mask, ws, out);
}

// Round 5
// 71.793 us; speedup vs baseline: 1.1191x; 1.1191x over previous
//
#include <hip/hip_runtime.h>
#include <math.h>

#define NB 64      // batch
#define NN 256     // elements per batch
#define NPAIRS 32640.0f   // N*(N-1)/2
#define EPSF 1e-8f

// ws layout (floats):
//   per-batch  [11][64]  at 0    : 0 noise,1 posmse,2 iou,3 layermse,4 conf,
//                                  5 golden,6 areaSum,7 area2Sum,8 cxSum,9 cySum,10 vc
//   per-block  [3][512]  at 704  : 0 rank, 1 overlap, 2 align
#define PB(q) ((q) * 64)
#define PW(q) (704 + (q) * 512)

// Block-wide sum for 256 threads (4 waves of 64). Result valid on ALL threads.
__device__ __forceinline__ float block_sum(float v, float* sred) {
    const int tid = threadIdx.x;
    #pragma unroll
    for (int off = 32; off > 0; off >>= 1) v += __shfl_down(v, off, 64);
    __syncthreads();                 // previous readers of sred are done
    if ((tid & 63) == 0) sred[tid >> 6] = v;
    __syncthreads();
    return sred[0] + sred[1] + sred[2] + sred[3];
}

// Three block-wide sums sharing one barrier pair (sred must hold >=12 floats).
__device__ __forceinline__ void block_sum3(float a, float b, float c, float* sred,
                                           float& ra, float& rb, float& rc) {
    const int tid = threadIdx.x;
    #pragma unroll
    for (int off = 32; off > 0; off >>= 1) {
        a += __shfl_down(a, off, 64);
        b += __shfl_down(b, off, 64);
        c += __shfl_down(c, off, 64);
    }
    __syncthreads();
    if ((tid & 63) == 0) {
        const int w = tid >> 6;
        sred[w] = a; sred[4 + w] = b; sred[8 + w] = c;
    }
    __syncthreads();
    ra = sred[0] + sred[1] + sred[2]  + sred[3];
    rb = sred[4] + sred[5] + sred[6]  + sred[7];
    rc = sred[8] + sred[9] + sred[10] + sred[11];
}

__global__ __launch_bounds__(256) void loss_main(
    const float* __restrict__ pn, const float* __restrict__ tn,
    const float* __restrict__ pl, const float* __restrict__ tl,
    const float* __restrict__ mask, float* __restrict__ ws)
{
    // packed pair fields: sA = {x1, y1, x2, y2}, sB = {cx, cy, area, p_layer},
    // sC = {t_layer, m}
    __shared__ float4 sA[NN], sB[NN];
    __shared__ float2 sC[NN];
    __shared__ float sred[12];

    const int b     = blockIdx.x >> 3;   // batch
    const int chunk = blockIdx.x & 7;    // pair-distance chunk / scalar-duty chunk
    const int i     = threadIdx.x;       // element within batch
    const int e     = b * NN + i;
    const float m   = mask[e];

    // vectorized row loads (rows are 24B-aligned -> float2 ok)
    const float2* pl2 = (const float2*)pl;
    const float2* tl2 = (const float2*)tl;
    const int r2 = e * 3;
    const float2 pla = pl2[r2 + 0], plb = pl2[r2 + 1], plc = pl2[r2 + 2];
    const float2 tlc = tl2[r2 + 2];

    const float p0 = pla.x * m, p1 = pla.y * m,
                p2 = plb.x * m, p3 = plb.y * m,
                p4 = plc.x * m, p5 = plc.y * m;
    const float t4 = tlc.x * m, t5 = tlc.y * m;

    const float x2v = p0 + p2, y2v = p1 + p3;
    const float areav = p2 * p3;
    const float cxe = p0 + 0.5f * p2, cye = p1 + 0.5f * p3;

    sA[i] = make_float4(p0, p1, x2v, y2v);
    sB[i] = make_float4(cxe, cye, areav, p4);
    sC[i] = make_float2(t4, m);
    __syncthreads();

    // ---------------- pairwise terms (this chunk's 16-dd range) -------------
    float rank = 0.f, ovl = 0.f, aln = 0.f;
    const int dd0 = chunk * 16 + 1;
    #pragma unroll 8
    for (int dd = dd0; dd < dd0 + 16; ++dd) {
        int j = (i + dd) & 255;
        if (dd == 128 && i >= 128) continue;   // dd=128 pairs counted once (i<j)
        float4 aj = sA[j];
        float4 bj = sB[j];
        float2 cj = sC[j];
        float pv = m * cj.y;
        // overlap
        float ow = fmaxf(fminf(x2v, aj.z) - fmaxf(p0, aj.x), 0.f);
        float oh = fmaxf(fminf(y2v, aj.w) - fmaxf(p1, aj.y), 0.f);
        ovl += ow * oh / (fminf(areav, bj.z) + EPSF) * pv;
        // alignment (6 edge types, dist<5 -> dist/5; /5 folded into 0.2f)
        float pen = 0.f, d;
        d = fabsf(p0  - aj.x); pen += (d < 5.f) ? d : 0.f;
        d = fabsf(x2v - aj.z); pen += (d < 5.f) ? d : 0.f;
        d = fabsf(p1  - aj.y); pen += (d < 5.f) ? d : 0.f;
        d = fabsf(y2v - aj.w); pen += (d < 5.f) ? d : 0.f;
        d = fabsf(cxe - bj.x); pen += (d < 5.f) ? d : 0.f;
        d = fabsf(cye - bj.y); pen += (d < 5.f) ? d : 0.f;
        aln += pen * 0.2f * pv;
        // ranking BCE on ordered (lo,hi)=(min(i,j),max(i,j)): diff = p[hi]-p[lo]
        bool ilt = (i < j);
        float dlo = ilt ? (bj.w - p4) : (p4 - bj.w);
        float ylo = (ilt ? (t4 < cj.x) : (cj.x < t4)) ? 1.f : 0.f;
        float sp  = __logf(1.f + __expf(-fabsf(dlo)));   // stable softplus core
        float sp_pos = sp + fmaxf(dlo, 0.f);             // softplus(+diff)
        float sp_neg = sp + fmaxf(-dlo, 0.f);            // softplus(-diff)
        rank += ylo * fminf(sp_neg, 100.f) + (1.f - ylo) * fminf(sp_pos, 100.f);
    }

    // pairwise per-block sums: one barrier pair for all three terms
    {
        float sr, so, sa;
        block_sum3(rank, ovl, aln, sred, sr, so, sa);
        if (i == 0) {
            ws[PW(0) + blockIdx.x] = sr;
            ws[PW(1) + blockIdx.x] = so;
            ws[PW(2) + blockIdx.x] = sa;
        }
    }

    // ---------------- elementwise terms: distributed across 8 chunks --------
    float s;
    switch (chunk) {
    case 0: {
        // noise SmoothL1 (only this chunk touches pn/tn)
        const float2* pn2 = (const float2*)pn;
        const float2* tn2 = (const float2*)tn;
        float noise = 0.f;
        #pragma unroll
        for (int k = 0; k < 3; ++k) {
            float2 a = pn2[r2 + k], bb = tn2[r2 + k];
            float d0 = fabsf(a.x * m - bb.x * m);
            float d1 = fabsf(a.y * m - bb.y * m);
            noise += (d0 < 1.f) ? 0.5f * d0 * d0 : d0 - 0.5f;
            noise += (d1 < 1.f) ? 0.5f * d1 * d1 : d1 - 0.5f;
        }
        s = block_sum(noise, sred); if (i == 0) ws[PB(0) + b] = s;
        break; }
    case 1: {
        const float2 tla = tl2[r2 + 0], tlb = tl2[r2 + 1];
        const float t0 = tla.x * m, t1 = tla.y * m,
                    t2 = tlb.x * m, t3 = tlb.y * m;
        float posmse = (p0 - t0) * (p0 - t0) + (p1 - t1) * (p1 - t1)
                     + (p2 - t2) * (p2 - t2) + (p3 - t3) * (p3 - t3);
        const float tx2 = t0 + t2, ty2 = t1 + t3;
        float iw = fmaxf(fminf(x2v, tx2) - fmaxf(p0, t0), 0.f);
        float ih = fmaxf(fminf(y2v, ty2) - fmaxf(p1, t1), 0.f);
        float inter = iw * ih;
        float iouL = 1.f - inter / (areav + t2 * t3 - inter + EPSF);
        float s0, s1, s2;
        block_sum3(posmse, iouL, 0.f, sred, s0, s1, s2);
        if (i == 0) { ws[PB(1) + b] = s0; ws[PB(2) + b] = s1; }
        break; }
    case 2: {
        float lmse = (p4 - t4) * (p4 - t4);
        float cmse = (p5 - t5) * (p5 - t5);
        float s0, s1, s2;
        block_sum3(lmse, cmse, 0.f, sred, s0, s1, s2);
        if (i == 0) { ws[PB(3) + b] = s0; ws[PB(4) + b] = s1; }
        break; }
    case 3: {
        float golden = fabsf(p2 / (p3 + EPSF) - 1.618f);
        s = block_sum(golden, sred); if (i == 0) ws[PB(5) + b] = s;
        break; }
    case 4: {
        float areaA = areav * m;
        s = block_sum(areaA, sred); if (i == 0) ws[PB(6) + b] = s;
        break; }
    case 5: {
        float areaA = areav * m;
        s = block_sum(areaA * areaA, sred); if (i == 0) ws[PB(7) + b] = s;
        break; }
    case 6: {
        float cxA = cxe * m, cyA = cye * m;
        float s0, s1, s2;
        block_sum3(cxA, cyA, 0.f, sred, s0, s1, s2);
        if (i == 0) { ws[PB(8) + b] = s0; ws[PB(9) + b] = s1; }
        break; }
    default: {
        s = block_sum(m, sred); if (i == 0) ws[PB(10) + b] = s;
        break; }
    }
}

__global__ __launch_bounds__(256) void loss_final(
    const float* __restrict__ ws, float* __restrict__ out)
{
    __shared__ float sred[12];
    __shared__ float bcx[NB], bcy[NB], bvc[NB];
    const int t = threadIdx.x;

    float v_noise = 0.f, v_pos = 0.f, v_iou = 0.f, v_lm = 0.f, v_cf = 0.f,
          v_go = 0.f, v_ar = 0.f, v_std = 0.f;
    if (t < NB) {
        v_noise = ws[PB(0) + t];
        v_pos   = ws[PB(1) + t];
        v_iou   = ws[PB(2) + t];
        v_lm    = ws[PB(3) + t];
        v_cf    = ws[PB(4) + t];
        v_go    = ws[PB(5) + t];
        v_ar    = ws[PB(6) + t];
        float a2 = ws[PB(7) + t];
        // per-row std, ddof=1
        float var = (a2 - v_ar * v_ar * (1.f / 256.f)) * (1.f / 255.f);
        v_std = sqrtf(fmaxf(var, 0.f));
        bcx[t] = ws[PB(8) + t];
        bcy[t] = ws[PB(9) + t];
        bvc[t] = ws[PB(10) + t];
    }
    // 512 pair-partials per term, 2 per thread
    float v_rank = ws[PW(0) + t] + ws[PW(0) + 256 + t];
    float v_ovl  = ws[PW(1) + t] + ws[PW(1) + 256 + t];
    float v_aln  = ws[PW(2) + t] + ws[PW(2) + 256 + t];
    __syncthreads();

    // faithful [B,B] balance broadcast: ocx[i,j] = sumcx[j]/(vc[i]+EPS)
    float v_bal = 0.f;
    if (t < NB) {
        float inv = 1.f / (bvc[t] + EPSF);
        for (int j = 0; j < NB; ++j) {
            v_bal += fabsf(bcx[j] * inv - 512.f) * (1.f / 512.f)
                   + fabsf(bcy[j] * inv - 512.f) * (1.f / 512.f);
        }
    }

    float S_noise, S_pos, S_iou, S_lm, S_cf, S_go, S_ar, S_std, S_bal,
          S_rank, S_ovl, S_aln;
    block_sum3(v_noise, v_pos, v_iou, sred, S_noise, S_pos, S_iou);
    block_sum3(v_lm,    v_cf,  v_go,  sred, S_lm,    S_cf,  S_go);
    block_sum3(v_ar,    v_std, v_bal, sred, S_ar,    S_std, S_bal);
    block_sum3(v_rank,  v_ovl, v_aln, sred, S_rank,  S_ovl, S_aln);

    if (t == 0) {
        const float BN = 64.f * 256.f;
        float noise_loss = S_noise / (BN * 6.f);
        float position   = S_pos / (BN * 4.f) + 0.5f * (S_iou / BN);
        float layer      = S_lm / BN + 0.3f * (S_rank / (64.f * NPAIRS));
        float conf       = S_cf / BN;
        float golden     = S_go / BN;
        float size_harm  = (S_std / 64.f) / (S_ar / BN + EPSF);
        float balance    = S_bal / 4096.f;
        float aes        = 0.1f * golden + 0.2f * size_harm + 0.15f * balance;
        float ovl        = S_ovl / (64.f * NPAIRS);
        float aln        = S_aln / (64.f * 6.f * NPAIRS);
        out[0] = noise_loss + position + 0.5f * layer + 0.3f * conf
               + 0.2f * aes + 0.8f * ovl + 0.4f * aln;
    }
}

extern "C" void kernel_launch(void* const* d_in, const int* in_sizes, int n_in,
                              void* d_out, int out_size, void* d_ws, size_t ws_size,
                              hipStream_t stream) {
    const float* pn   = (const float*)d_in[0];
    const float* tn   = (const float*)d_in[1];
    const float* pl   = (const float*)d_in[2];
    const float* tl   = (const float*)d_in[3];
    const float* mask = (const float*)d_in[4];
    float* ws  = (float*)d_ws;
    float* out = (float*)d_out;
    hipLaunchKernelGGL(loss_main, dim3(512), dim3(256), 0, stream,
                       pn, tn, pl, tl, mask, ws);
    hipLaunchKernelGGL(loss_final, dim3(1), dim3(256), 0, stream, ws, out);
}

// Round 6
// 71.366 us; speedup vs baseline: 1.1258x; 1.0060x over previous
//
#include <hip/hip_runtime.h>
#include <math.h>

#define NB 64      // batch
#define NN 256     // elements per batch
#define NPAIRS 32640.0f   // N*(N-1)/2
#define EPSF 1e-8f

// ws layout (floats):
//   per-batch  [11][64]   at 0   : 0 noise,1 posmse,2 iou,3 layermse,4 conf,
//                                  5 golden,6 areaSum,7 area2Sum,8 cxSum,9 cySum,10 vc
//   per-block  [3][1024]  at 704 : 0 rank, 1 overlap, 2 align
#define PB(q) ((q) * 64)
#define PW(q) (704 + (q) * 1024)

// Block-wide sum for 256 threads (4 waves of 64). Result valid on ALL threads.
__device__ __forceinline__ float block_sum(float v, float* sred) {
    const int tid = threadIdx.x;
    #pragma unroll
    for (int off = 32; off > 0; off >>= 1) v += __shfl_down(v, off, 64);
    __syncthreads();
    if ((tid & 63) == 0) sred[tid >> 6] = v;
    __syncthreads();
    return sred[0] + sred[1] + sred[2] + sred[3];
}

// Three block-wide sums sharing one barrier pair (sred holds >=12 floats).
__device__ __forceinline__ void block_sum3(float a, float b, float c, float* sred,
                                           float& ra, float& rb, float& rc) {
    const int tid = threadIdx.x;
    #pragma unroll
    for (int off = 32; off > 0; off >>= 1) {
        a += __shfl_down(a, off, 64);
        b += __shfl_down(b, off, 64);
        c += __shfl_down(c, off, 64);
    }
    __syncthreads();
    if ((tid & 63) == 0) {
        const int w = tid >> 6;
        sred[w] = a; sred[4 + w] = b; sred[8 + w] = c;
    }
    __syncthreads();
    ra = sred[0] + sred[1] + sred[2]  + sred[3];
    rb = sred[4] + sred[5] + sred[6]  + sred[7];
    rc = sred[8] + sred[9] + sred[10] + sred[11];
}

// Single-wave (64-lane) sum; result valid on lane 0.
__device__ __forceinline__ float wave_sum(float v) {
    #pragma unroll
    for (int off = 32; off > 0; off >>= 1) v += __shfl_down(v, off, 64);
    return v;
}

__global__ __launch_bounds__(256) void loss_main(
    const float* __restrict__ pn, const float* __restrict__ tn,
    const float* __restrict__ pl, const float* __restrict__ tl,
    const float* __restrict__ mask, float* __restrict__ ws)
{
    // packed pair fields: sA = {x1, y1, x2, y2}, sB = {cx, cy, area, p_layer},
    // sC = {t_layer, m}
    __shared__ float4 sA[NN], sB[NN];
    __shared__ float2 sC[NN];
    __shared__ float sred[12];

    const int b     = blockIdx.x >> 4;   // batch
    const int chunk = blockIdx.x & 15;   // pair-distance chunk / scalar-duty chunk
    const int i     = threadIdx.x;       // element within batch
    const int e     = b * NN + i;
    const float m   = mask[e];

    // vectorized row loads (rows are 24B-aligned -> float2 ok)
    const float2* pl2 = (const float2*)pl;
    const float2* tl2 = (const float2*)tl;
    const int r2 = e * 3;
    const float2 pla = pl2[r2 + 0], plb = pl2[r2 + 1], plc = pl2[r2 + 2];
    const float2 tlc = tl2[r2 + 2];

    const float p0 = pla.x * m, p1 = pla.y * m,
                p2 = plb.x * m, p3 = plb.y * m,
                p4 = plc.x * m, p5 = plc.y * m;
    const float t4 = tlc.x * m, t5 = tlc.y * m;

    const float x2v = p0 + p2, y2v = p1 + p3;
    const float areav = p2 * p3;
    const float cxe = p0 + 0.5f * p2, cye = p1 + 0.5f * p3;

    sA[i] = make_float4(p0, p1, x2v, y2v);
    sB[i] = make_float4(cxe, cye, areav, p4);
    sC[i] = make_float2(t4, m);
    __syncthreads();

    // ---------------- pairwise terms (this chunk's 8-dd range) --------------
    float rank = 0.f, ovl = 0.f, aln = 0.f;
    const int dd0 = chunk * 8 + 1;
    #pragma unroll
    for (int k = 0; k < 8; ++k) {
        const int dd = dd0 + k;
        int j = (i + dd) & 255;
        if (dd == 128 && i >= 128) continue;   // dd=128 pairs counted once (i<j)
        float4 aj = sA[j];
        float4 bj = sB[j];
        float2 cj = sC[j];
        float pv = m * cj.y;
        // overlap
        float ow = fmaxf(fminf(x2v, aj.z) - fmaxf(p0, aj.x), 0.f);
        float oh = fmaxf(fminf(y2v, aj.w) - fmaxf(p1, aj.y), 0.f);
        ovl += ow * oh / (fminf(areav, bj.z) + EPSF) * pv;
        // alignment (6 edge types, dist<5 -> dist/5; /5 folded into 0.2f)
        float pen = 0.f, d;
        d = fabsf(p0  - aj.x); pen += (d < 5.f) ? d : 0.f;
        d = fabsf(x2v - aj.z); pen += (d < 5.f) ? d : 0.f;
        d = fabsf(p1  - aj.y); pen += (d < 5.f) ? d : 0.f;
        d = fabsf(y2v - aj.w); pen += (d < 5.f) ? d : 0.f;
        d = fabsf(cxe - bj.x); pen += (d < 5.f) ? d : 0.f;
        d = fabsf(cye - bj.y); pen += (d < 5.f) ? d : 0.f;
        aln += pen * 0.2f * pv;
        // ranking BCE on ordered (lo,hi)=(min(i,j),max(i,j)): diff = p[hi]-p[lo]
        bool ilt = (i < j);
        float dlo = ilt ? (bj.w - p4) : (p4 - bj.w);
        float ylo = (ilt ? (t4 < cj.x) : (cj.x < t4)) ? 1.f : 0.f;
        float sp  = __logf(1.f + __expf(-fabsf(dlo)));   // stable softplus core
        float sp_pos = sp + fmaxf(dlo, 0.f);             // softplus(+diff)
        float sp_neg = sp + fmaxf(-dlo, 0.f);            // softplus(-diff)
        rank += ylo * fminf(sp_neg, 100.f) + (1.f - ylo) * fminf(sp_pos, 100.f);
    }

    // pairwise per-block sums: one barrier pair for all three terms
    {
        float sr, so, sa;
        block_sum3(rank, ovl, aln, sred, sr, so, sa);
        if (i == 0) {
            ws[PW(0) + blockIdx.x] = sr;
            ws[PW(1) + blockIdx.x] = so;
            ws[PW(2) + blockIdx.x] = sa;
        }
    }

    // ---------------- elementwise terms: one duty per chunk -----------------
    float v = 0.f;
    bool have = true;
    switch (chunk) {
    case 0: {
        // noise SmoothL1 (only this chunk touches pn/tn)
        const float2* pn2 = (const float2*)pn;
        const float2* tn2 = (const float2*)tn;
        float noise = 0.f;
        #pragma unroll
        for (int k = 0; k < 3; ++k) {
            float2 a = pn2[r2 + k], bb = tn2[r2 + k];
            float d0 = fabsf(a.x * m - bb.x * m);
            float d1 = fabsf(a.y * m - bb.y * m);
            noise += (d0 < 1.f) ? 0.5f * d0 * d0 : d0 - 0.5f;
            noise += (d1 < 1.f) ? 0.5f * d1 * d1 : d1 - 0.5f;
        }
        v = noise;
        break; }
    case 1: {
        const float2 tla = tl2[r2 + 0], tlb = tl2[r2 + 1];
        const float t0 = tla.x * m, t1 = tla.y * m,
                    t2 = tlb.x * m, t3 = tlb.y * m;
        v = (p0 - t0) * (p0 - t0) + (p1 - t1) * (p1 - t1)
          + (p2 - t2) * (p2 - t2) + (p3 - t3) * (p3 - t3);
        break; }
    case 2: {
        const float2 tla = tl2[r2 + 0], tlb = tl2[r2 + 1];
        const float t0 = tla.x * m, t1 = tla.y * m,
                    t2 = tlb.x * m, t3 = tlb.y * m;
        const float tx2 = t0 + t2, ty2 = t1 + t3;
        float iw = fmaxf(fminf(x2v, tx2) - fmaxf(p0, t0), 0.f);
        float ih = fmaxf(fminf(y2v, ty2) - fmaxf(p1, t1), 0.f);
        float inter = iw * ih;
        v = 1.f - inter / (areav + t2 * t3 - inter + EPSF);
        break; }
    case 3: v = (p4 - t4) * (p4 - t4); break;
    case 4: v = (p5 - t5) * (p5 - t5); break;
    case 5: v = fabsf(p2 / (p3 + EPSF) - 1.618f); break;
    case 6: v = areav * m; break;
    case 7: { float a = areav * m; v = a * a; break; }
    case 8: v = cxe * m; break;
    case 9: v = cye * m; break;
    case 10: v = m; break;
    default: have = false; break;
    }
    if (have) {
        float s = block_sum(v, sred);
        if (i == 0) ws[PB(chunk) + b] = s;
    }
}

__global__ __launch_bounds__(64) void loss_final(
    const float* __restrict__ ws, float* __restrict__ out)
{
    const int t = threadIdx.x;   // one wave; t in [0,64) = batch index

    // per-batch scalars (NB == 64 == wave width)
    float v_noise = ws[PB(0) + t];
    float v_pos   = ws[PB(1) + t];
    float v_iou   = ws[PB(2) + t];
    float v_lm    = ws[PB(3) + t];
    float v_cf    = ws[PB(4) + t];
    float v_go    = ws[PB(5) + t];
    float v_ar    = ws[PB(6) + t];
    float a2      = ws[PB(7) + t];
    float v_cx    = ws[PB(8) + t];
    float v_cy    = ws[PB(9) + t];
    float v_vc    = ws[PB(10) + t];
    // per-row std, ddof=1
    float var   = (a2 - v_ar * v_ar * (1.f / 256.f)) * (1.f / 255.f);
    float v_std = sqrtf(fmaxf(var, 0.f));

    // 1024 pair-partials per term, 16 per lane
    float v_rank = 0.f, v_ovl = 0.f, v_aln = 0.f;
    #pragma unroll
    for (int k = 0; k < 16; ++k) {
        v_rank += ws[PW(0) + k * 64 + t];
        v_ovl  += ws[PW(1) + k * 64 + t];
        v_aln  += ws[PW(2) + k * 64 + t];
    }

    // faithful [B,B] balance broadcast: ocx[i,j] = sumcx[j]/(vc[i]+EPS)
    float inv = 1.f / (v_vc + EPSF);
    float v_bal = 0.f;
    for (int j = 0; j < NB; ++j) {
        float cxj = __shfl(v_cx, j, 64);
        float cyj = __shfl(v_cy, j, 64);
        v_bal += fabsf(cxj * inv - 512.f) * (1.f / 512.f)
               + fabsf(cyj * inv - 512.f) * (1.f / 512.f);
    }

    float S_noise = wave_sum(v_noise);
    float S_pos   = wave_sum(v_pos);
    float S_iou   = wave_sum(v_iou);
    float S_lm    = wave_sum(v_lm);
    float S_cf    = wave_sum(v_cf);
    float S_go    = wave_sum(v_go);
    float S_ar    = wave_sum(v_ar);
    float S_std   = wave_sum(v_std);
    float S_bal   = wave_sum(v_bal);
    float S_rank  = wave_sum(v_rank);
    float S_ovl   = wave_sum(v_ovl);
    float S_aln   = wave_sum(v_aln);

    if (t == 0) {
        const float BN = 64.f * 256.f;
        float noise_loss = S_noise / (BN * 6.f);
        float position   = S_pos / (BN * 4.f) + 0.5f * (S_iou / BN);
        float layer      = S_lm / BN + 0.3f * (S_rank / (64.f * NPAIRS));
        float conf       = S_cf / BN;
        float golden     = S_go / BN;
        float size_harm  = (S_std / 64.f) / (S_ar / BN + EPSF);
        float balance    = S_bal / 4096.f;
        float aes        = 0.1f * golden + 0.2f * size_harm + 0.15f * balance;
        float ovl        = S_ovl / (64.f * NPAIRS);
        float aln        = S_aln / (64.f * 6.f * NPAIRS);
        out[0] = noise_loss + position + 0.5f * layer + 0.3f * conf
               + 0.2f * aes + 0.8f * ovl + 0.4f * aln;
    }
}

extern "C" void kernel_launch(void* const* d_in, const int* in_sizes, int n_in,
                              void* d_out, int out_size, void* d_ws, size_t ws_size,
                              hipStream_t stream) {
    const float* pn   = (const float*)d_in[0];
    const float* tn   = (const float*)d_in[1];
    const float* pl   = (const float*)d_in[2];
    const float* tl   = (const float*)d_in[3];
    const float* mask = (const float*)d_in[4];
    float* ws  = (float*)d_ws;
    float* out = (float*)d_out;
    hipLaunchKernelGGL(loss_main, dim3(1024), dim3(256), 0, stream,
                       pn, tn, pl, tl, mask, ws);
    hipLaunchKernelGGL(loss_final, dim3(1), dim3(64), 0, stream, ws, out);
}